// Round 6
// baseline (140.470 us; speedup 1.0000x reference)
//
#include <hip/hip_runtime.h>
#include <hip/hip_bf16.h>
#include <math.h>

#define B_   8
#define C_   32
#define H_   256
#define W_   256
#define NPIX (B_*C_*H_*W_)   // offset of logdet in d_out

// LDS geometry: 2 staged rows x 260 px x 32 ch (bf16), p = w+1, halo zeros at
// p=0 and p=257.  dword(r,p,cp) = r*4160 + p*16 + ((cp>>2) ^ ((p>>2)&3))*4 + (cp&3)
#define PW    260
#define ROWDW (PW*16)          // 4160 dwords per staged row
#define ROWB  (ROWDW*4)        // 16640 bytes

typedef __attribute__((ext_vector_type(8))) short short8;   // bf16x8 MFMA A/B frag
typedef __attribute__((ext_vector_type(4))) float f32x4;    // fp32x4 MFMA C/D frag

static __device__ __forceinline__ short f2bf(float f) {
    union { __hip_bfloat16 h; short s; } u; u.h = __float2bfloat16(f); return u.s;
}
static __device__ __forceinline__ int packbf(float a, float b) {
    return (int)(unsigned short)f2bf(a) | ((int)(unsigned short)f2bf(b) << 16);
}

// ---------------------------------------------------------------------------
// Prep: weight-norm -> bf16.
//   w1b[o*192 + tap*32 + c]                       (tap = kh*3+kw)
//   w2b[j*64 + slot]: hidden-dim permutation so conv2 B-frags are lane-local:
//     channel c (mt=c>>4, q=(c>>2)&3, reg=c&3) -> slot (mt>>1)*32+q*8+(mt&1)*4+reg
// ---------------------------------------------------------------------------
__global__ __launch_bounds__(64) void prep_kernel(
    const float* __restrict__ v1, const float* __restrict__ g1,
    const float* __restrict__ v2, const float* __restrict__ g2,
    short* __restrict__ w1b, short* __restrict__ w2b,
    float* __restrict__ logdet)
{
    const int t   = threadIdx.x;   // 0..63
    const int bid = blockIdx.x;    // 0..127
    if (bid < 64) {
        const int o = bid;
        float a0 = v1[o*192 + t];
        float a1 = v1[o*192 + t + 64];
        float a2 = v1[o*192 + t + 128];
        float s  = a0*a0 + a1*a1 + a2*a2;
        #pragma unroll
        for (int m = 32; m >= 1; m >>= 1) s += __shfl_xor(s, m, 64);
        const float inv = g1[o] / sqrtf(s);
        const int e0 = t, e1 = t + 64, e2 = t + 128;   // src idx = c*6 + tap
        w1b[o*192 + (e0%6)*32 + e0/6] = f2bf(a0*inv);
        w1b[o*192 + (e1%6)*32 + e1/6] = f2bf(a1*inv);
        w1b[o*192 + (e2%6)*32 + e2/6] = f2bf(a2*inv);
        if (bid == 0 && t < B_) logdet[t] = 0.f;       // zero logdet every launch
    } else {
        const int j = bid - 64;
        float a = v2[j*64 + t];
        float s = a*a;
        #pragma unroll
        for (int m = 32; m >= 1; m >>= 1) s += __shfl_xor(s, m, 64);
        const float inv = g2[j] / sqrtf(s);
        const int mt = t >> 4, r = t & 15;
        const int slot = (mt >> 1)*32 + ((r >> 2) << 3) + ((mt & 1) << 2) + (r & 3);
        w2b[j*64 + slot] = f2bf(a*inv);
    }
}

// ---------------------------------------------------------------------------
// Fused MFMA kernel: one block per (b, h); 4 waves, 64 px each; 2048 blocks.
// Single barrier: stage rows h-2,h-1 -> bar -> conv1 -> ELU -> conv2 -> epi.
// conv1: D1[o][px] (A = weights, B = x-patch) -> lane holds o=4q+reg, px=lrow
// conv2: lane-local B-frags (hidden dim pre-permuted in w2b).
// ---------------------------------------------------------------------------
__global__ __launch_bounds__(256) void flow_kernel(
    const float* __restrict__ x,
    const short* __restrict__ w1b, const short* __restrict__ w2b,
    const float* __restrict__ b1,  const float* __restrict__ b2,
    float* __restrict__ out, float* __restrict__ logdet)
{
    __shared__ int ldsI[2*ROWDW];   // 33280 B

    const int bi0 = blockIdx.x;            // 0..2047
    const int bi  = (bi0 & 7) * 256 + (bi0 >> 3);   // XCD k owns image k
    const int b   = bi >> 8;
    const int h   = bi & 255;

    const int tid  = threadIdx.x;
    const int l    = tid & 63;
    const int wv   = tid >> 6;
    const int lrow = l & 15;
    const int q    = l >> 4;

    const float* xb = x + (size_t)b * (C_*H_*W_);
    float* ob       = out + (size_t)b * (C_*H_*W_);

    // ---- stage rows h-2 (r=0), h-1 (r=1): 2 units/thread ------------------
    {
        const int r  = tid >> 7;           // staged row index
        const int hr = h - 2 + r;
        const int u0 = tid & 127;
        #pragma unroll
        for (int ui = 0; ui < 2; ++ui) {
            const int unit = u0 + ui*128;  // 0..255
            const int qd   = unit & 63;    // pixel quad
            const int cg   = unit >> 6;    // channel group (8 ch)
            const int w4   = qd << 2;
            const int c8   = cg << 3;
            if (hr >= 0) {
                f32x4 qv[8];
                #pragma unroll
                for (int j = 0; j < 8; ++j)
                    qv[j] = *(const f32x4*)(xb + (size_t)(c8 + j)*(H_*W_) + (size_t)hr*W_ + w4);
                #pragma unroll
                for (int pp = 0; pp < 4; ++pp) {
                    const int p  = w4 + pp + 1;
                    const int sw = (p >> 2) & 3;
                    int4 d;
                    d.x = packbf(qv[0][pp], qv[1][pp]);
                    d.y = packbf(qv[2][pp], qv[3][pp]);
                    d.z = packbf(qv[4][pp], qv[5][pp]);
                    d.w = packbf(qv[6][pp], qv[7][pp]);
                    *(int4*)&ldsI[r*ROWDW + p*16 + ((cg ^ sw) << 2)] = d;
                }
            } else {
                #pragma unroll
                for (int pp = 0; pp < 4; ++pp) {
                    const int p  = w4 + pp + 1;
                    const int sw = (p >> 2) & 3;
                    *(int4*)&ldsI[r*ROWDW + p*16 + ((cg ^ sw) << 2)] = (int4){0,0,0,0};
                }
            }
        }
        // halo columns p=0 and p=257: zero all 16 dwords each, both rows
        if (tid < 16) {
            const int rz  = tid >> 3;              // row
            const int pz  = (tid >> 2) & 1 ? 257 : 0;
            const int seg = tid & 3;
            *(int4*)&ldsI[rz*ROWDW + pz*16 + seg*4] = (int4){0,0,0,0};
        }
    }
    __syncthreads();

    // ---- conv1: D1[o][px], bias pre-loaded into acc ------------------------
    f32x4 acc1[4][4];
    #pragma unroll
    for (int mt = 0; mt < 4; ++mt) {
        const f32x4 bv = *(const f32x4*)(b1 + mt*16 + 4*q);
        #pragma unroll
        for (int nt = 0; nt < 4; ++nt) acc1[mt][nt] = bv;
    }

    #pragma unroll
    for (int tap = 0; tap < 6; ++tap) {
        const int rb = (tap < 3) ? 0 : ROWB;
        const int dw = (tap % 3) - 1;
        short8 wf[4];
        #pragma unroll
        for (int mt = 0; mt < 4; ++mt)
            wf[mt] = *(const short8*)(w1b + (mt*16 + lrow)*192 + tap*32 + q*8);
        #pragma unroll
        for (int nt = 0; nt < 4; ++nt) {
            const int p = wv*64 + nt*16 + lrow + dw + 1;    // halo-shifted
            const int byteoff = rb + p*64 + ((q ^ ((p >> 2) & 3)) << 4);
            const short8 xf = *(const short8*)((const char*)ldsI + byteoff);
            #pragma unroll
            for (int mt = 0; mt < 4; ++mt)
                acc1[mt][nt] = __builtin_amdgcn_mfma_f32_16x16x32_bf16(
                                   wf[mt], xf, acc1[mt][nt], 0, 0, 0);
        }
    }

    // ---- ELU in-register ---------------------------------------------------
    #pragma unroll
    for (int mt = 0; mt < 4; ++mt)
        #pragma unroll
        for (int nt = 0; nt < 4; ++nt)
            #pragma unroll
            for (int rg = 0; rg < 4; ++rg) {
                const float v = acc1[mt][nt][rg];
                acc1[mt][nt][rg] = v > 0.f ? v : (__expf(v) - 1.f);
            }

    // ---- conv2: lane-local B-frags (hidden dim pre-permuted in w2b) -------
    short8 a2f[2][4];
    #pragma unroll
    for (int kt = 0; kt < 2; ++kt)
        #pragma unroll
        for (int mt2 = 0; mt2 < 4; ++mt2)
            a2f[kt][mt2] = *(const short8*)(w2b + (mt2*16 + lrow)*64 + kt*32 + q*8);

    f32x4 acc2[4][4];
    #pragma unroll
    for (int nt = 0; nt < 4; ++nt) {
        short8 bf0, bf1;
        #pragma unroll
        for (int rg = 0; rg < 4; ++rg) {
            bf0[rg]     = f2bf(acc1[0][nt][rg]);
            bf0[rg + 4] = f2bf(acc1[1][nt][rg]);
            bf1[rg]     = f2bf(acc1[2][nt][rg]);
            bf1[rg + 4] = f2bf(acc1[3][nt][rg]);
        }
        #pragma unroll
        for (int mt2 = 0; mt2 < 4; ++mt2) {
            f32x4 t0 = __builtin_amdgcn_mfma_f32_16x16x32_bf16(
                           a2f[0][mt2], bf0, (f32x4){0.f,0.f,0.f,0.f}, 0, 0, 0);
            acc2[mt2][nt] = __builtin_amdgcn_mfma_f32_16x16x32_bf16(
                           a2f[1][mt2], bf1, t0, 0, 0, 0);
        }
    }

    // ---- epilogue: sigmoid/affine/logdet, all lane-local -------------------
    f32x4 b2m[2], b2s[2];
    #pragma unroll
    for (int mt2 = 0; mt2 < 2; ++mt2) {
        b2m[mt2] = *(const f32x4*)(b2 + mt2*16 + 4*q);
        b2s[mt2] = *(const f32x4*)(b2 + 32 + mt2*16 + 4*q);
    }

    float ldsum = 0.f;
    #pragma unroll
    for (int nt = 0; nt < 4; ++nt) {
        const int px = wv*64 + nt*16 + lrow;
        const int colbase = h*W_ + px;
        #pragma unroll
        for (int mt2 = 0; mt2 < 2; ++mt2)
            #pragma unroll
            for (int rg = 0; rg < 4; ++rg) {
                const float mu = acc2[mt2][nt][rg]     + b2m[mt2][rg];
                const float z  = acc2[mt2 + 2][nt][rg] + b2s[mt2][rg] + 2.f;
                const float sc = 1.f / (1.f + __expf(-z));
                ldsum += __logf(sc);
                const int j = mt2*16 + 4*q + rg;
                const size_t idx = (size_t)j * (H_*W_) + colbase;
                ob[idx] = xb[idx] * sc + mu;
            }
    }

    // ---- logdet: per-wave reduce + atomic ---------------------------------
    #pragma unroll
    for (int m = 32; m >= 1; m >>= 1) ldsum += __shfl_xor(ldsum, m, 64);
    if (l == 0) atomicAdd(&logdet[b], ldsum);
}

// ---------------------------------------------------------------------------
extern "C" void kernel_launch(void* const* d_in, const int* in_sizes, int n_in,
                              void* d_out, int out_size, void* d_ws, size_t ws_size,
                              hipStream_t stream)
{
    const float* x  = (const float*)d_in[0];
    const float* v1 = (const float*)d_in[1];
    const float* g1 = (const float*)d_in[2];
    const float* b1 = (const float*)d_in[3];
    const float* v2 = (const float*)d_in[4];
    const float* g2 = (const float*)d_in[5];
    const float* b2 = (const float*)d_in[6];

    float* out    = (float*)d_out;
    float* logdet = out + NPIX;

    short* w1b = (short*)d_ws;          // 12288 bf16
    short* w2b = w1b + 12288;           //  4096 bf16

    prep_kernel<<<128, 64, 0, stream>>>(v1, g1, v2, g2, w1b, w2b, logdet);
    flow_kernel<<<B_ * H_, 256, 0, stream>>>(x, w1b, w2b, b1, b2, out, logdet);
}